// Round 1
// baseline (19.895 us; speedup 1.0000x reference)
//
#include <hip/hip_runtime.h>

#define NPROT 128
#define NATOMS 16384
#define BLK_PER_PROT 8
#define THREADS 256
#define GROUPS_PER_BLOCK (NATOMS / BLK_PER_PROT / 4)   // 512 groups of 4 atoms
#define GROUPS_PER_THREAD (GROUPS_PER_BLOCK / THREADS) // 2

// ---------------- Stage 1: masked moment reduction ----------------
// Per (protein, chunk) block: accumulate 17 sums over its 2048-atom slice:
// [0..2] sum x, [3..5] sum y, [6..14] sum x_i*y_j, [15] sum|x|^2, [16] sum|y|^2
__global__ __launch_bounds__(THREADS) void kabsch_reduce_kernel(
    const float* __restrict__ x, const float* __restrict__ y,
    const int* __restrict__ num_atoms, float* __restrict__ ws)
{
    const int b = blockIdx.x / BLK_PER_PROT;
    const int chunk = blockIdx.x % BLK_PER_PROT;
    const int na = num_atoms[b];
    const float4* px = (const float4*)(x + (size_t)b * 3 * NATOMS);
    const float4* py = (const float4*)(y + (size_t)b * 3 * NATOMS);

    float acc[17];
    #pragma unroll
    for (int i = 0; i < 17; ++i) acc[i] = 0.f;

    const int t = threadIdx.x;
    #pragma unroll
    for (int it = 0; it < GROUPS_PER_THREAD; ++it) {
        const int g = chunk * GROUPS_PER_BLOCK + it * THREADS + t; // group of 4 atoms
        const float4 fx0 = px[3 * g + 0];
        const float4 fx1 = px[3 * g + 1];
        const float4 fx2 = px[3 * g + 2];
        const float4 fy0 = py[3 * g + 0];
        const float4 fy1 = py[3 * g + 1];
        const float4 fy2 = py[3 * g + 2];
        const int a0 = g * 4;
        const float xs[4][3] = {{fx0.x, fx0.y, fx0.z}, {fx0.w, fx1.x, fx1.y},
                                {fx1.z, fx1.w, fx2.x}, {fx2.y, fx2.z, fx2.w}};
        const float ys[4][3] = {{fy0.x, fy0.y, fy0.z}, {fy0.w, fy1.x, fy1.y},
                                {fy1.z, fy1.w, fy2.x}, {fy2.y, fy2.z, fy2.w}};
        #pragma unroll
        for (int k = 0; k < 4; ++k) {
            const float m = (a0 + k < na) ? 1.f : 0.f;
            const float X0 = xs[k][0] * m, X1 = xs[k][1] * m, X2 = xs[k][2] * m;
            const float Y0 = ys[k][0] * m, Y1 = ys[k][1] * m, Y2 = ys[k][2] * m;
            acc[0] += X0;  acc[1] += X1;  acc[2] += X2;
            acc[3] += Y0;  acc[4] += Y1;  acc[5] += Y2;
            acc[6]  += X0 * Y0;  acc[7]  += X0 * Y1;  acc[8]  += X0 * Y2;
            acc[9]  += X1 * Y0;  acc[10] += X1 * Y1;  acc[11] += X1 * Y2;
            acc[12] += X2 * Y0;  acc[13] += X2 * Y1;  acc[14] += X2 * Y2;
            acc[15] += X0 * X0 + X1 * X1 + X2 * X2;
            acc[16] += Y0 * Y0 + Y1 * Y1 + Y2 * Y2;
        }
    }

    // wave64 butterfly reduce, then cross-wave via LDS
    #pragma unroll
    for (int i = 0; i < 17; ++i) {
        float v = acc[i];
        #pragma unroll
        for (int off = 32; off; off >>= 1) v += __shfl_down(v, off);
        acc[i] = v;
    }
    __shared__ float red[THREADS / 64][17];
    const int wave = t >> 6, lane = t & 63;
    if (lane == 0) {
        #pragma unroll
        for (int i = 0; i < 17; ++i) red[wave][i] = acc[i];
    }
    __syncthreads();
    if (t == 0) {
        float* dst = ws + ((size_t)b * BLK_PER_PROT + chunk) * 17;
        #pragma unroll
        for (int i = 0; i < 17; ++i)
            dst[i] = red[0][i] + red[1][i] + red[2][i] + red[3][i];
    }
}

// ---------------- Stage 2: per-protein Kabsch closed form (double) ----------------
__global__ __launch_bounds__(NPROT) void kabsch_finalize_kernel(
    const float* __restrict__ ws, const int* __restrict__ num_atoms,
    float* __restrict__ out)
{
    const int b = threadIdx.x;
    if (b >= NPROT) return;

    double s[17];
    #pragma unroll
    for (int i = 0; i < 17; ++i) s[i] = 0.0;
    #pragma unroll
    for (int c = 0; c < BLK_PER_PROT; ++c) {
        const float* p = ws + ((size_t)b * BLK_PER_PROT + c) * 17;
        #pragma unroll
        for (int i = 0; i < 17; ++i) s[i] += (double)p[i];
    }

    const double n = (double)num_atoms[b];
    const double mx0 = s[0] / n, mx1 = s[1] / n, mx2 = s[2] / n;
    const double my0 = s[3] / n, my1 = s[4] / n, my2 = s[5] / n;

    // C[i][j] = sum x_i y_j - n * mx_i * my_j
    double C00 = s[6]  - n * mx0 * my0, C01 = s[7]  - n * mx0 * my1, C02 = s[8]  - n * mx0 * my2;
    double C10 = s[9]  - n * mx1 * my0, C11 = s[10] - n * mx1 * my1, C12 = s[11] - n * mx1 * my2;
    double C20 = s[12] - n * mx2 * my0, C21 = s[13] - n * mx2 * my1, C22 = s[14] - n * mx2 * my2;

    const double E0 = (s[15] - n * (mx0 * mx0 + mx1 * mx1 + mx2 * mx2))
                    + (s[16] - n * (my0 * my0 + my1 * my1 + my2 * my2));

    // A = C^T C (symmetric PSD); singular values of C = sqrt(eig(A))
    const double a00 = C00 * C00 + C10 * C10 + C20 * C20;
    const double a01 = C00 * C01 + C10 * C11 + C20 * C21;
    const double a02 = C00 * C02 + C10 * C12 + C20 * C22;
    const double a11 = C01 * C01 + C11 * C11 + C21 * C21;
    const double a12 = C01 * C02 + C11 * C12 + C21 * C22;
    const double a22 = C02 * C02 + C12 * C12 + C22 * C22;

    // trigonometric closed-form eigenvalues of symmetric 3x3, sorted e0>=e1>=e2
    const double p1 = a01 * a01 + a02 * a02 + a12 * a12;
    const double q = (a00 + a11 + a22) / 3.0;
    const double b00 = a00 - q, b11 = a11 - q, b22 = a22 - q;
    const double p2 = b00 * b00 + b11 * b11 + b22 * b22 + 2.0 * p1;
    double e0, e1, e2;
    if (p2 <= 0.0) {
        e0 = e1 = e2 = q;
    } else {
        const double p = sqrt(p2 / 6.0);
        const double inv = 1.0 / p;
        const double c00 = b00 * inv, c01 = a01 * inv, c02 = a02 * inv;
        const double c11 = b11 * inv, c12 = a12 * inv, c22 = b22 * inv;
        double r = 0.5 * (c00 * (c11 * c22 - c12 * c12)
                        - c01 * (c01 * c22 - c12 * c02)
                        + c02 * (c01 * c12 - c11 * c02));
        r = fmin(1.0, fmax(-1.0, r));
        const double phi = acos(r) / 3.0;
        e0 = q + 2.0 * p * cos(phi);
        e2 = q + 2.0 * p * cos(phi + 2.0943951023931953); // + 2*pi/3
        e1 = 3.0 * q - e0 - e2;
    }
    const double s0 = sqrt(fmax(e0, 0.0));
    const double s1 = sqrt(fmax(e1, 0.0));
    const double s2 = sqrt(fmax(e2, 0.0));

    const double detC = C00 * (C11 * C22 - C12 * C21)
                      - C01 * (C10 * C22 - C12 * C20)
                      + C02 * (C10 * C21 - C11 * C20);
    const double sum_s = s0 + s1 + (detC < 0.0 ? -s2 : s2);

    const double msd = fmax(E0 - 2.0 * sum_s, 0.0) / n;
    out[b] = (float)sqrt(msd + 1e-8);
}

extern "C" void kernel_launch(void* const* d_in, const int* in_sizes, int n_in,
                              void* d_out, int out_size, void* d_ws, size_t ws_size,
                              hipStream_t stream) {
    const float* x = (const float*)d_in[0];
    const float* y = (const float*)d_in[1];
    const int* num_atoms = (const int*)d_in[2];
    float* out = (float*)d_out;
    float* ws = (float*)d_ws;  // NPROT * BLK_PER_PROT * 17 floats = 69.6 KB

    kabsch_reduce_kernel<<<NPROT * BLK_PER_PROT, THREADS, 0, stream>>>(x, y, num_atoms, ws);
    kabsch_finalize_kernel<<<1, NPROT, 0, stream>>>(ws, num_atoms, out);
}

// Round 4
// 16.824 us; speedup vs baseline: 1.1825x; 1.1825x over previous
//
#include <hip/hip_runtime.h>

#define NPROT 128
#define NATOMS 16384
#define THREADS 1024
#define WAVES (THREADS / 64)                    // 16 waves per block
#define GROUPS_PER_THREAD (NATOMS / 4 / THREADS) // 4 groups of 4 atoms per thread

// Single-dispatch Kabsch RMSD: one block per protein (128 blocks x 1024 threads).
// Each block streams its protein's coords, accumulates 17 masked moment sums
// ([0..2] sum x, [3..5] sum y, [6..14] sum x_i*y_j, [15] |x|^2, [16] |y|^2),
// reduces block-locally, and thread 0 runs the f64 closed-form finalize.
// No workspace, no cross-block communication, graph-replay safe by construction.
__global__ __launch_bounds__(THREADS) void kabsch_onepass_kernel(
    const float* __restrict__ x, const float* __restrict__ y,
    const int* __restrict__ num_atoms, float* __restrict__ out)
{
    const int b = blockIdx.x;
    const int na = num_atoms[b];
    const float4* px = (const float4*)(x + (size_t)b * 3 * NATOMS);
    const float4* py = (const float4*)(y + (size_t)b * 3 * NATOMS);

    float acc[17];
    #pragma unroll
    for (int i = 0; i < 17; ++i) acc[i] = 0.f;

    const int t = threadIdx.x;
    #pragma unroll
    for (int it = 0; it < GROUPS_PER_THREAD; ++it) {
        const int g = it * THREADS + t;   // group of 4 atoms
        const int a0 = g * 4;
        if (a0 >= na) continue;           // fully padded group: no loads at all
        const float4 fx0 = px[3 * g + 0];
        const float4 fx1 = px[3 * g + 1];
        const float4 fx2 = px[3 * g + 2];
        const float4 fy0 = py[3 * g + 0];
        const float4 fy1 = py[3 * g + 1];
        const float4 fy2 = py[3 * g + 2];
        const float xs[4][3] = {{fx0.x, fx0.y, fx0.z}, {fx0.w, fx1.x, fx1.y},
                                {fx1.z, fx1.w, fx2.x}, {fx2.y, fx2.z, fx2.w}};
        const float ys[4][3] = {{fy0.x, fy0.y, fy0.z}, {fy0.w, fy1.x, fy1.y},
                                {fy1.z, fy1.w, fy2.x}, {fy2.y, fy2.z, fy2.w}};
        #pragma unroll
        for (int k = 0; k < 4; ++k) {
            const float m = (a0 + k < na) ? 1.f : 0.f;
            const float X0 = xs[k][0] * m, X1 = xs[k][1] * m, X2 = xs[k][2] * m;
            const float Y0 = ys[k][0] * m, Y1 = ys[k][1] * m, Y2 = ys[k][2] * m;
            acc[0] += X0;  acc[1] += X1;  acc[2] += X2;
            acc[3] += Y0;  acc[4] += Y1;  acc[5] += Y2;
            acc[6]  += X0 * Y0;  acc[7]  += X0 * Y1;  acc[8]  += X0 * Y2;
            acc[9]  += X1 * Y0;  acc[10] += X1 * Y1;  acc[11] += X1 * Y2;
            acc[12] += X2 * Y0;  acc[13] += X2 * Y1;  acc[14] += X2 * Y2;
            acc[15] += X0 * X0 + X1 * X1 + X2 * X2;
            acc[16] += Y0 * Y0 + Y1 * Y1 + Y2 * Y2;
        }
    }

    // wave64 butterfly reduce, then cross-wave via LDS
    #pragma unroll
    for (int i = 0; i < 17; ++i) {
        float v = acc[i];
        #pragma unroll
        for (int off = 32; off; off >>= 1) v += __shfl_down(v, off);
        acc[i] = v;
    }
    __shared__ float red[WAVES][17];
    __shared__ double stot[17];
    const int wave = t >> 6, lane = t & 63;
    if (lane == 0) {
        #pragma unroll
        for (int i = 0; i < 17; ++i) red[wave][i] = acc[i];
    }
    __syncthreads();

    // threads 0..16 each sum one moment column across the 16 waves (f64)
    if (t < 17) {
        double v = 0.0;
        #pragma unroll
        for (int w = 0; w < WAVES; ++w) v += (double)red[w][t];
        stot[t] = v;
    }
    __syncthreads();

    if (t != 0) return;

    // ---------------- Finalize: Kabsch closed form (double) ----------------
    double s[17];
    #pragma unroll
    for (int i = 0; i < 17; ++i) s[i] = stot[i];

    const double n = (double)na;
    const double mx0 = s[0] / n, mx1 = s[1] / n, mx2 = s[2] / n;
    const double my0 = s[3] / n, my1 = s[4] / n, my2 = s[5] / n;

    // C[i][j] = sum x_i y_j - n * mx_i * my_j
    double C00 = s[6]  - n * mx0 * my0, C01 = s[7]  - n * mx0 * my1, C02 = s[8]  - n * mx0 * my2;
    double C10 = s[9]  - n * mx1 * my0, C11 = s[10] - n * mx1 * my1, C12 = s[11] - n * mx1 * my2;
    double C20 = s[12] - n * mx2 * my0, C21 = s[13] - n * mx2 * my1, C22 = s[14] - n * mx2 * my2;

    const double E0 = (s[15] - n * (mx0 * mx0 + mx1 * mx1 + mx2 * mx2))
                    + (s[16] - n * (my0 * my0 + my1 * my1 + my2 * my2));

    // A = C^T C (symmetric PSD); singular values of C = sqrt(eig(A))
    const double a00 = C00 * C00 + C10 * C10 + C20 * C20;
    const double a01 = C00 * C01 + C10 * C11 + C20 * C21;
    const double a02 = C00 * C02 + C10 * C12 + C20 * C22;
    const double a11 = C01 * C01 + C11 * C11 + C21 * C21;
    const double a12 = C01 * C02 + C11 * C12 + C21 * C22;
    const double a22 = C02 * C02 + C12 * C12 + C22 * C22;

    // trigonometric closed-form eigenvalues of symmetric 3x3, sorted e0>=e1>=e2
    const double p1 = a01 * a01 + a02 * a02 + a12 * a12;
    const double q = (a00 + a11 + a22) / 3.0;
    const double b00 = a00 - q, b11 = a11 - q, b22 = a22 - q;
    const double p2 = b00 * b00 + b11 * b11 + b22 * b22 + 2.0 * p1;
    double e0, e1, e2;
    if (p2 <= 0.0) {
        e0 = e1 = e2 = q;
    } else {
        const double p = sqrt(p2 / 6.0);
        const double inv = 1.0 / p;
        const double c00 = b00 * inv, c01 = a01 * inv, c02 = a02 * inv;
        const double c11 = b11 * inv, c12 = a12 * inv, c22 = b22 * inv;
        double r = 0.5 * (c00 * (c11 * c22 - c12 * c12)
                        - c01 * (c01 * c22 - c12 * c02)
                        + c02 * (c01 * c12 - c11 * c02));
        r = fmin(1.0, fmax(-1.0, r));
        const double phi = acos(r) / 3.0;
        e0 = q + 2.0 * p * cos(phi);
        e2 = q + 2.0 * p * cos(phi + 2.0943951023931953); // + 2*pi/3
        e1 = 3.0 * q - e0 - e2;
    }
    const double s0 = sqrt(fmax(e0, 0.0));
    const double s1 = sqrt(fmax(e1, 0.0));
    const double s2 = sqrt(fmax(e2, 0.0));

    const double detC = C00 * (C11 * C22 - C12 * C21)
                      - C01 * (C10 * C22 - C12 * C20)
                      + C02 * (C10 * C21 - C11 * C20);
    const double sum_s = s0 + s1 + (detC < 0.0 ? -s2 : s2);

    const double msd = fmax(E0 - 2.0 * sum_s, 0.0) / n;
    out[b] = (float)sqrt(msd + 1e-8);
}

extern "C" void kernel_launch(void* const* d_in, const int* in_sizes, int n_in,
                              void* d_out, int out_size, void* d_ws, size_t ws_size,
                              hipStream_t stream) {
    const float* x = (const float*)d_in[0];
    const float* y = (const float*)d_in[1];
    const int* num_atoms = (const int*)d_in[2];
    float* out = (float*)d_out;
    (void)d_ws; (void)ws_size;

    kabsch_onepass_kernel<<<NPROT, THREADS, 0, stream>>>(x, y, num_atoms, out);
}